// Round 1
// 422.571 us; speedup vs baseline: 1.1221x; 1.1221x over previous
//
#include <hip/hip_runtime.h>

// ---------------------------------------------------------------------------
// SelfInteraction: 2 layers of (tensor-square -> invariant-gated MLP -> equiv
// linear) + residual + eq-layernorm, N=16384 rows, C=128, all fp32 I/O.
// fp16 hi/lo split-precision MFMA GEMMs (22-bit effective mantissa).
// This revision:
//   * LDS XOR-swizzle (byte bits 4-5 ^= bits 7-8) on BOTH sides (pre-swizzled
//     global source for global_load_lds + swizzled ds_read) -> kills the
//     8-way bank conflict on the 64B-stride fragment reads.
//   * GEMM2 MODE2: gating fused into the epilogue -> G matrix never exists.
//   * e1 eliminated: A1 (sc' hi/lo) emitted directly by e0 (layer 0) and by
//     e3's layernorm path (layer 1) from lane-resident values.
//   * GEMM0 + GEMMV merged into one 512-block dispatch (gemm_pair).
//   * 8 prep_w launches -> 1 prep_all.
// ---------------------------------------------------------------------------

typedef _Float16 half8 __attribute__((ext_vector_type(8)));
typedef float floatx4 __attribute__((ext_vector_type(4)));

static inline int cdiv_h(int a, int b){ return (a + b - 1) / b; }

// ---------------------------- device helpers -------------------------------

__device__ __forceinline__ void stage16(const char* gaddr, char* lds_wave_base){
  // dest = wave-uniform base + lane*16 (measured semantics, learn_hip m104/m108)
  __builtin_amdgcn_global_load_lds((const __attribute__((address_space(1))) unsigned int*)gaddr,
                                   (__attribute__((address_space(3))) unsigned int*)lds_wave_base,
                                   16, 0, 0);
}

__device__ __forceinline__ float wave_sum64(float x){
  #pragma unroll
  for (int m = 32; m; m >>= 1) x += __shfl_xor(x, m, 64);
  return x;
}

__device__ __forceinline__ void split_store(_Float16* p0, _Float16* p1, float v){
  _Float16 hi = (_Float16)v;
  *p0 = hi;
  *p1 = (_Float16)(v - (float)hi);
}

// ---------------------------- weight prep ----------------------------------
// All 8 weight-prep jobs in one launch. w row-major (K, ldw); writes BT'
// [col][3K]: seg0=hi, seg1=lo, seg2=hi (dup).
__global__ __launch_bounds__(256) void prep_all(const float* __restrict__ w1,
                                                const float* __restrict__ w2,
                                                const float* __restrict__ w0,
                                                const float* __restrict__ wv,
                                                _Float16* __restrict__ W){
  const int PER_L = 475136;                      // 147456+245760+49152+32768
  int idx = blockIdx.x*256 + threadIdx.x;
  if (idx >= 2*PER_L) return;
  int l = idx / PER_L;
  int r = idx - l*PER_L;
  const float RS384 = 0.051031036307982884f;     // 1/sqrt(384)
  _Float16* WL = W + (size_t)l*1425408;
  const float* src; _Float16* dst; int K, ldw, col, k; float scale;
  if (r < 147456){                               // w1: 384x384
    src = w1 + (size_t)l*147456; dst = WL;            K = 384; ldw = 384; scale = RS384;
    col = r / 384; k = r - col*384;
  } else if (r < 393216){                        // w2: 384x768, first 640 cols
    r -= 147456;
    src = w2 + (size_t)l*294912; dst = WL + 442368;   K = 384; ldw = 768; scale = RS384;
    col = r / 384; k = r - col*384;
  } else if (r < 442368){                        // w0: 384x128
    r -= 393216;
    src = w0 + (size_t)l*49152;  dst = WL + 1179648;  K = 384; ldw = 128; scale = RS384;
    col = r / 384; k = r - col*384;
  } else {                                       // wv: 256x128
    r -= 442368;
    src = wv + (size_t)l*32768;  dst = WL + 1327104;  K = 256; ldw = 128; scale = 0.0625f;
    col = r / 256; k = r - col*256;
  }
  float v = src[(size_t)k*ldw + col] * scale;
  _Float16 hi = (_Float16)v;
  _Float16 lo = (_Float16)(v - (float)hi);
  size_t b = (size_t)col*3*K + k;
  dst[b]       = hi;
  dst[b + K]   = lo;
  dst[b + 2*K] = hi;
}

// ---------------------------- E0: unpack x + build sc' ---------------------
// One wave per row via LDS stage. Writes S, V (d-major) AND A1 = sc' hi/lo.
__global__ __launch_bounds__(256) void e0_fused(const float* __restrict__ x,
                                                float* __restrict__ S,
                                                float* __restrict__ V,
                                                _Float16* __restrict__ A1,
                                                int row0){
  __shared__ alignas(16) float lx[4][512];
  const int n0 = blockIdx.x*4;
  const int tid = threadIdx.x;
  const float4* xs = (const float4*)(x + (size_t)(row0 + n0)*512);
  float4* ls = (float4*)(&lx[0][0]);
  ls[tid]       = xs[tid];
  ls[tid + 256] = xs[tid + 256];
  __syncthreads();
  const int w = tid >> 6, lane = tid & 63;
  const int n = n0 + w;
  const float* row = &lx[w][0];
  #pragma unroll
  for (int h = 0; h < 2; ++h){
    int ch = h*64 + lane;
    float s = row[ch];
    S[(size_t)n*128 + ch] = s;
    float vv = 0.f;
    #pragma unroll
    for (int d = 0; d < 3; ++d){
      float vd = row[128 + ch*3 + d];
      V[((size_t)n*3 + d)*128 + ch] = vd;
      vv += vd*vd;
    }
    float vals[3] = { s, s*s, vv * 0.5773502691896258f };   // 1/sqrt(3)
    #pragma unroll
    for (int q = 0; q < 3; ++q){
      size_t b = (size_t)n*768 + q*128 + ch;
      split_store(&A1[b], &A1[b + 384], vals[q]);
    }
  }
}

// ---------------------------- E3: residual + LN / final --------------------
// one wave per row; doln=1: eq_layernorm back into state AND emit next
// layer's A1 = sc' hi/lo; doln=0: write final output.
__global__ __launch_bounds__(256) void e3_fin(float* __restrict__ S, float* __restrict__ V,
                                              const float* __restrict__ OS, const float* __restrict__ OV,
                                              const float* __restrict__ g0, const float* __restrict__ g1,
                                              float* __restrict__ out, _Float16* __restrict__ A1,
                                              int row0, int doln){
  int n = blockIdx.x*4 + (threadIdx.x >> 6);
  int lane = threadIdx.x & 63;
  size_t sb = (size_t)n*128;
  size_t vb = (size_t)n*384;
  float s0 = S[sb + lane]      + OS[sb + lane];
  float s1 = S[sb + 64 + lane] + OS[sb + 64 + lane];
  float v[6];
  #pragma unroll
  for (int k = 0; k < 6; ++k) v[k] = V[vb + k*64 + lane] + OV[vb + k*64 + lane];

  if (doln){
    float mu = wave_sum64(s0 + s1) * (1.0f/128.0f);
    float d0 = s0 - mu, d1 = s1 - mu;
    float var = wave_sum64(d0*d0 + d1*d1) * (1.0f/128.0f);
    float sd = sqrtf(var + 1e-6f);
    float vvsum = 0.f;
    #pragma unroll
    for (int k = 0; k < 6; ++k) vvsum += v[k]*v[k];
    float rms = sqrtf(wave_sum64(vvsum) * (1.0f/384.0f) + 1e-6f);
    float s0n = d0 / sd * g0[lane];
    float s1n = d1 / sd * g0[64 + lane];
    S[sb + lane]      = s0n;
    S[sb + 64 + lane] = s1n;
    float vn[6];
    #pragma unroll
    for (int k = 0; k < 6; ++k){
      int j = k*64 + lane;
      vn[k] = v[k] / rms * g1[j & 127];
      V[vb + j] = vn[k];
    }
    // emit A1 = sc' = [s, s^2, |v|^2/sqrt3] hi/lo for the next layer
    float vv_a = vn[0]*vn[0] + vn[2]*vn[2] + vn[4]*vn[4];   // ch = lane
    float vv_b = vn[1]*vn[1] + vn[3]*vn[3] + vn[5]*vn[5];   // ch = 64+lane
    float va[3] = { s0n, s0n*s0n, vv_a * 0.5773502691896258f };
    float vbv[3]= { s1n, s1n*s1n, vv_b * 0.5773502691896258f };
    #pragma unroll
    for (int q = 0; q < 3; ++q){
      size_t ba = (size_t)n*768 + q*128 + lane;
      split_store(&A1[ba], &A1[ba + 384], va[q]);
      size_t bb = ba + 64;
      split_store(&A1[bb], &A1[bb + 384], vbv[q]);
    }
  } else {
    size_t ob = (size_t)(row0 + n)*512;
    out[ob + lane]      = s0;
    out[ob + 64 + lane] = s1;
    #pragma unroll
    for (int k = 0; k < 6; ++k){
      int j = k*64 + lane;
      int d = j >> 7, ch = j & 127;
      out[ob + 128 + ch*3 + d] = v[k];
    }
  }
}

// ---------------------------- split-GEMM main loop -------------------------
// C[M x ncols] = A[M x 2*kbase (hi|lo)] x BT[ncols x 3*kbase]^T
// 128x128 tile, 4 waves (each 64x64 = 4x4 MFMA tiles), 16x16x32 f16 MFMA,
// double-buffered LDS staged with global_load_lds width-16.
// LDS XOR-swizzle: physical_byte = logical_byte ^ (((logical>>7)&3)<<4).
// Involution; dest of global_load_lds stays linear (lane*16), the SOURCE is
// pre-swizzled; reads apply the same XOR (rule #21 both-sides pattern).
__device__ __forceinline__ void gemm_mainloop(const _Float16* __restrict__ A,
                                              const _Float16* __restrict__ BT,
                                              int lda, int kbase, int m0, int c0,
                                              _Float16 (&lA)[2][4096],
                                              _Float16 (&lB)[2][4096],
                                              floatx4 (&acc)[4][4]){
  const int nsc  = kbase >> 5;       // chunks per segment
  const int nch  = 3*nsc;
  const int ldbt = 3*kbase;
  const int tid  = threadIdx.x;
  const int wave = tid >> 6, lane = tid & 63;
  const int wm = wave & 1, wn = wave >> 1;
  const int r = lane & 15, kg = lane >> 4;
  const int slot = kg ^ ((r >> 1) & 3);          // swizzled 16B slot for reads

  auto stage = [&](int c, int buf){
    const int ka = ((c < nsc) ? c : c - nsc) << 5;   // A seg map: hi,hi,lo
    const int kb = c << 5;
    #pragma unroll
    for (int p = 0; p < 2; ++p){
      const int lbase = wave*1024 + p*4096;          // wave-uniform byte base
      const int off = lbase + lane*16;
      const int row = off >> 6;
      const int bir = (off & 63) ^ (((off >> 7) & 3) << 4);  // pre-swizzled src
      const char* ga = (const char*)A  + (((size_t)(m0 + row))*lda  + ka)*2 + bir;
      stage16(ga, (char*)(&lA[buf][0]) + lbase);
      const char* gb = (const char*)BT + (((size_t)(c0 + row))*ldbt + kb)*2 + bir;
      stage16(gb, (char*)(&lB[buf][0]) + lbase);
    }
  };

  stage(0, 0);
  for (int c = 0; c < nch; ++c){
    __syncthreads();                      // drains vmcnt -> buf[c&1] ready
    if (c + 1 < nch) stage(c + 1, (c + 1) & 1);
    const char* a_ = (const char*)&lA[c & 1][0];
    const char* b_ = (const char*)&lB[c & 1][0];
    half8 af[4], bf[4];
    #pragma unroll
    for (int mt = 0; mt < 4; ++mt)
      af[mt] = *(const half8*)(a_ + ((wm*64 + mt*16 + r)*64 + slot*16));
    #pragma unroll
    for (int nt = 0; nt < 4; ++nt)
      bf[nt] = *(const half8*)(b_ + ((wn*64 + nt*16 + r)*64 + slot*16));
    #pragma unroll
    for (int mt = 0; mt < 4; ++mt)
      #pragma unroll
      for (int nt = 0; nt < 4; ++nt)
        acc[mt][nt] = __builtin_amdgcn_mfma_f32_16x16x32_f16(af[mt], bf[nt], acc[mt][nt], 0, 0, 0);
  }
}

// MODE 0: plain f32 store. MODE 1: silu + hi/lo split into SP (GEMM2's h').
// MODE 2: fused gating epilogue (replaces e2_gate + the G matrix):
//   cols <384 : A1 <- (A1hi+A1lo) * g  (hi/lo, in place)
//   cols>=384 : A4[(n*3+d)*512+mm] <- vec[n,mm,d] * g  (hi/lo)
template<int MODE>
__global__ __launch_bounds__(256) void gemm_split(const _Float16* __restrict__ A,
                                                  const _Float16* __restrict__ BT,
                                                  float* __restrict__ C,
                                                  _Float16* __restrict__ SP,
                                                  const float* __restrict__ S,
                                                  const float* __restrict__ V,
                                                  _Float16* __restrict__ A1,
                                                  _Float16* __restrict__ A4,
                                                  int lda, int kbase, int ldc){
  __shared__ alignas(16) _Float16 lA[2][4096];   // 128 rows x 32 halves
  __shared__ alignas(16) _Float16 lB[2][4096];
  const int m0 = blockIdx.x << 7, c0 = blockIdx.y << 7;
  floatx4 acc[4][4];
  #pragma unroll
  for (int i = 0; i < 4; ++i)
    #pragma unroll
    for (int j = 0; j < 4; ++j) acc[i][j] = (floatx4){0.f, 0.f, 0.f, 0.f};

  gemm_mainloop(A, BT, lda, kbase, m0, c0, lA, lB, acc);

  const int wave = threadIdx.x >> 6, lane = threadIdx.x & 63;
  const int wm = wave & 1, wn = wave >> 1;
  const int r = lane & 15, kg = lane >> 4;

  #pragma unroll
  for (int mt = 0; mt < 4; ++mt){
    #pragma unroll
    for (int nt = 0; nt < 4; ++nt){
      #pragma unroll
      for (int i = 0; i < 4; ++i){
        const int row = m0 + wm*64 + mt*16 + kg*4 + i;   // C/D: row = quad*4+i
        const int col = c0 + wn*64 + nt*16 + r;          //      col = lane&15
        float g = acc[mt][nt][i];
        if (MODE == 0){
          C[(size_t)row*ldc + col] = g;
        } else if (MODE == 1){
          float h = g / (1.0f + __expf(-g));             // silu
          split_store(&SP[(size_t)row*768 + col], &SP[(size_t)row*768 + 384 + col], h);
        } else {
          if (c0 < 384){
            size_t b = (size_t)row*768 + col;
            float sc = (float)A1[b] + (float)A1[b + 384];
            split_store(&A1[b], &A1[b + 384], sc * g);
          } else {
            int mm = col - 384;                          // 0..255
            int ch = mm & 127;
            float gm = g;
            if (c0 == 512) gm *= 1.4142135623730951f * S[(size_t)row*128 + ch];
            #pragma unroll
            for (int d = 0; d < 3; ++d){
              float val = V[((size_t)row*3 + d)*128 + ch] * gm;
              size_t b = ((size_t)row*3 + d)*512 + mm;
              split_store(&A4[b], &A4[b + 256], val);
            }
          }
        }
      }
    }
  }
}

// GEMM0 (A1 x W0 -> OS) and GEMMV (A4 x WV -> OV) in a single dispatch:
// blocks [0,nb0) do problem 0, blocks [nb0,..) do problem 1. ldc=128, c0=0.
__global__ __launch_bounds__(256) void gemm_pair(const _Float16* __restrict__ Aa,
                                                 const _Float16* __restrict__ Ba,
                                                 float* __restrict__ Ca, int nb0,
                                                 const _Float16* __restrict__ Ab,
                                                 const _Float16* __restrict__ Bb,
                                                 float* __restrict__ Cb){
  __shared__ alignas(16) _Float16 lA[2][4096];
  __shared__ alignas(16) _Float16 lB[2][4096];
  const _Float16 *A, *BT; float* C; int lda, kbase, m0;
  if ((int)blockIdx.x < nb0){
    A = Aa; BT = Ba; C = Ca; lda = 768; kbase = 384; m0 = (int)blockIdx.x << 7;
  } else {
    A = Ab; BT = Bb; C = Cb; lda = 512; kbase = 256; m0 = ((int)blockIdx.x - nb0) << 7;
  }
  floatx4 acc[4][4];
  #pragma unroll
  for (int i = 0; i < 4; ++i)
    #pragma unroll
    for (int j = 0; j < 4; ++j) acc[i][j] = (floatx4){0.f, 0.f, 0.f, 0.f};

  gemm_mainloop(A, BT, lda, kbase, m0, 0, lA, lB, acc);

  const int wave = threadIdx.x >> 6, lane = threadIdx.x & 63;
  const int wm = wave & 1, wn = wave >> 1;
  const int r = lane & 15, kg = lane >> 4;
  #pragma unroll
  for (int mt = 0; mt < 4; ++mt)
    #pragma unroll
    for (int nt = 0; nt < 4; ++nt)
      #pragma unroll
      for (int i = 0; i < 4; ++i){
        const int row = m0 + wm*64 + mt*16 + kg*4 + i;
        const int col = wn*64 + nt*16 + r;
        C[(size_t)row*128 + col] = acc[mt][nt][i];
      }
}

// ---------------------------- host launcher --------------------------------

extern "C" void kernel_launch(void* const* d_in, const int* in_sizes, int n_in,
                              void* d_out, int out_size, void* d_ws, size_t ws_size,
                              hipStream_t stream){
  const float* x  = (const float*)d_in[0];
  const float* w1 = (const float*)d_in[1];
  const float* w2 = (const float*)d_in[2];
  const float* w0 = (const float*)d_in[3];
  const float* wv = (const float*)d_in[4];
  const float* g0 = (const float*)d_in[5];
  const float* g1 = (const float*)d_in[6];
  float* out = (float*)d_out;
  const int N = in_sizes[0] / 512;                 // 16384

  // split-weight arena: per layer 1,425,408 halves
  const size_t HL = 1425408;
  _Float16* W = (_Float16*)d_ws;
  const size_t wbytes = 2*HL*2;                    // 5,701,632 B

  // pick N-chunking that fits ws (activations cost 10240 B/row now — no G)
  int cnum = 128;
  for (int cc = 1; cc <= 128; cc <<= 1){
    size_t need = wbytes + (size_t)(N/cc)*10240;
    if (need <= ws_size){ cnum = cc; break; }
  }
  const int R = N / cnum;                          // multiple of 128

  char* p = (char*)d_ws + wbytes;
  float*    Sst = (float*)p;     p += (size_t)R*512;
  float*    Vst = (float*)p;     p += (size_t)R*1536;
  _Float16* A1  = (_Float16*)p;  p += (size_t)R*1536;   // sc' then gated sc'
  _Float16* A2  = (_Float16*)p;  p += (size_t)R*1536;   // h'
  _Float16* A4  = (_Float16*)p;  p += (size_t)R*3072;   // gated vec' (3R x 512)
  float*    OS  = (float*)p;     p += (size_t)R*512;
  float*    OV  = (float*)p;     p += (size_t)R*1536;

  // weight prep (runs every call; ws is re-poisoned before each timed launch)
  prep_all<<<cdiv_h(2*475136,256),256,0,stream>>>(w1, w2, w0, wv, W);

  for (int chk = 0; chk < cnum; ++chk){
    const int row0 = chk*R;
    e0_fused<<<R/4,256,0,stream>>>(x, Sst, Vst, A1, row0);
    for (int l = 0; l < 2; ++l){
      _Float16* W1p = W + (size_t)l*HL;
      _Float16* W2p = W1p + 442368;
      _Float16* W0p = W1p + 1179648;
      _Float16* WVp = W1p + 1327104;
      gemm_split<1><<<dim3(R/128,3),256,0,stream>>>(A1, W1p, nullptr, A2,
          nullptr, nullptr, nullptr, nullptr, 768, 384, 0);
      gemm_split<2><<<dim3(R/128,5),256,0,stream>>>(A2, W2p, nullptr, nullptr,
          Sst, Vst, A1, A4, 768, 384, 0);
      gemm_pair<<<R/32,256,0,stream>>>(A1, W0p, OS, R/128, A4, WVp, OV);
      e3_fin<<<R/4,256,0,stream>>>(Sst, Vst, OS, OV, g0, g1, out, A1, row0, (l == 0) ? 1 : 0);
    }
  }
}